// Round 8
// baseline (223.102 us; speedup 1.0000x reference)
//
#include <hip/hip_runtime.h>
#include <hip/hip_bf16.h>
#include <stdint.h>

#define KN 32
#define D  128
#define NNODES 20000
#define GRID 2500
#define ITERS 4            // 2 nodes/iter * 4 iters * 2500 blocks = 20000
#define VOCAB 100000

#define CONV_BLOCKS 6250                     // VOCAB*D/2048
#define PACK_BLOCKS 192
#define SV1_BLOCKS  ((NNODES + 63) / 64)     // 313
#define AUX_BLOCKS  (CONV_BLOCKS + PACK_BLOCKS + SV1_BLOCKS)

typedef __bf16 bf16;
typedef __bf16 bf16x8 __attribute__((ext_vector_type(8)));
typedef float  f32x4  __attribute__((ext_vector_type(4)));

// bf16 e_u LDS layout: 8 chunks/node; chunk c (1024 B, one GL2LDS) holds rows
// {c, c+8, c+16, c+24} (256 B each) + 16 B pad -> 520 bf16 elems per chunk.
// Row r -> elem (r&7)*CHUNK_E + (r>>3)*128.
#define CHUNK_E 520
#define EU_NODE_E (8 * CHUNK_E)      // 4160 bf16 per node
#define H_STRIDE 136                 // bf16 elems; 68 dw, %32=4
#define CHUNK_DW 260                 // fp32 staging chunk (rows c, c+16 + pad)

#define GL2LDS(src, dst) __builtin_amdgcn_global_load_lds(                 \
    (const __attribute__((address_space(1))) void*)(src),                  \
    (__attribute__((address_space(3))) void*)(dst), 16, 0, 0)

#define MFMA(a, b, c) __builtin_amdgcn_mfma_f32_16x16x32_bf16((a), (b), (c), 0, 0, 0)

// ---------------------------------------------------------------------------
// Fused aux kernel — ONE dispatch, blockIdx-partitioned (the three jobs are
// data-independent; separate dispatches serialize in graph capture):
//   [0, 6250)       : u2e fp32 -> bf16 table
//   [6250, 6442)    : pack W1/W2 -> bf16 MFMA B-frag order
//   [6442, 6755)    : sv1[n] = self_feats[n] . W1_self^T  (64 nodes/block,
//                     reads fp32 u2e + fp32 W1 directly)
// ---------------------------------------------------------------------------
__global__ __launch_bounds__(256) void aux_kernel(
    const float* __restrict__ u2e,
    const float* __restrict__ W1,
    const float* __restrict__ W2,
    const int*   __restrict__ nodes,
    bf16*  __restrict__ u2e_bf,
    bf16*  __restrict__ w1p,
    bf16*  __restrict__ w2p,
    float* __restrict__ sv1t)
{
    const int b = blockIdx.x;
    const int t = threadIdx.x;

    if (b < CONV_BLOCKS) {
        size_t i = ((size_t)b * 256 + t) * 8;
        float4 a = *(const float4*)(u2e + i);
        float4 c = *(const float4*)(u2e + i + 4);
        bf16x8 v;
        v[0]=(bf16)a.x; v[1]=(bf16)a.y; v[2]=(bf16)a.z; v[3]=(bf16)a.w;
        v[4]=(bf16)c.x; v[5]=(bf16)c.y; v[6]=(bf16)c.z; v[7]=(bf16)c.w;
        *(bf16x8*)(u2e_bf + i) = v;
        return;
    }
    if (b < CONV_BLOCKS + PACK_BLOCKS) {
        int g = (b - CONV_BLOCKS) * 256 + t;
        if (g < 32768) {
            int j = g & 7, lane = (g >> 3) & 63, kt = (g >> 9) & 7, nt = g >> 12;
            int d = nt * 16 + (lane & 15);
            int f = kt * 32 + ((lane >> 4) << 3) + j;
            w1p[g] = (bf16)W1[d * 256 + f];
        } else if (g < 49152) {
            int u = g - 32768;
            int j = u & 7, lane = (u >> 3) & 63, kt = (u >> 9) & 3, nt = u >> 11;
            int e  = nt * 16 + (lane & 15);
            int dd = kt * 32 + ((lane >> 4) << 3) + j;
            w2p[u] = (bf16)W2[e * 128 + dd];
        }
        return;
    }
    // ---- sv1: 64 nodes per block ----
    {
        __shared__ alignas(16) float sr[2 * 16 * CHUNK_DW];   // 33280 B

        const int sb   = b - CONV_BLOCKS - PACK_BLOCKS;
        const int base = sb * 64;
        const int lane = t & 63;
        const int wave = t >> 6;
        const int ln15 = lane & 15;
        const int quad = lane >> 4;

        // stage: wave w stages chunks [(w>>1)*8 .. +8) of row-group (w&1)
        {
            const int grp  = wave & 1;
            const int cb   = (wave >> 1) * 8;
            const int half = lane >> 5;
            const int colb = (lane & 31) << 4;
            #pragma unroll
            for (int j = 0; j < 8; ++j) {
                int chunk = cb + j;
                int row = base + grp * 32 + chunk + half * 16;
                int node = nodes[row < NNODES ? row : NNODES - 1];
                GL2LDS((const char*)(u2e + (size_t)node * D) + colb,
                       sr + grp * 16 * CHUNK_DW + chunk * CHUNK_DW);
            }
        }
        __syncthreads();

        const float* g  = sr + (wave & 1) * 16 * CHUNK_DW;
        const int    r0 = ln15 * CHUNK_DW;

        #pragma unroll 1
        for (int np = (wave >> 1) * 2; np <= (wave >> 1) * 2 + 1; ++np) {
            const int nt0 = np * 2;
            bf16x8 b0[4], b1[4];
            #pragma unroll
            for (int kt = 0; kt < 4; ++kt) {   // B-frags from fp32 W1 self half
                const float* s0 = W1 + (size_t)(nt0 * 16 + ln15) * 256 + 128 + kt * 32 + quad * 8;
                const float* s1 = W1 + (size_t)((nt0 + 1) * 16 + ln15) * 256 + 128 + kt * 32 + quad * 8;
                f32x4 u0 = *(const f32x4*)(s0), u1 = *(const f32x4*)(s0 + 4);
                f32x4 v0 = *(const f32x4*)(s1), v1 = *(const f32x4*)(s1 + 4);
                bf16x8 bb0, bb1;
                #pragma unroll
                for (int e = 0; e < 4; ++e) {
                    bb0[e] = (bf16)u0[e]; bb0[4 + e] = (bf16)u1[e];
                    bb1[e] = (bf16)v0[e]; bb1[4 + e] = (bf16)v1[e];
                }
                b0[kt] = bb0; b1[kt] = bb1;
            }
            f32x4 c00 = {0.f,0.f,0.f,0.f}, c01 = c00, c10 = c00, c11 = c00;
            #pragma unroll
            for (int kt = 0; kt < 4; ++kt) {
                int off = kt * 32 + quad * 8;
                f32x4 u0 = *(const f32x4*)(g + r0 + off);
                f32x4 u1 = *(const f32x4*)(g + r0 + off + 4);
                f32x4 v0 = *(const f32x4*)(g + r0 + 128 + off);
                f32x4 v1 = *(const f32x4*)(g + r0 + 128 + off + 4);
                bf16x8 a0, a1;
                #pragma unroll
                for (int e = 0; e < 4; ++e) {
                    a0[e] = (bf16)u0[e]; a0[4 + e] = (bf16)u1[e];
                    a1[e] = (bf16)v0[e]; a1[4 + e] = (bf16)v1[e];
                }
                c00 = MFMA(a0, b0[kt], c00);
                c01 = MFMA(a0, b1[kt], c01);
                c10 = MFMA(a1, b0[kt], c10);
                c11 = MFMA(a1, b1[kt], c11);
            }
            #pragma unroll
            for (int r = 0; r < 4; ++r) {
                int row = quad * 4 + r;
                int gr0 = base + (wave & 1) * 32 + row;
                int gr1 = gr0 + 16;
                if (gr0 < NNODES) {
                    sv1t[(size_t)gr0 * D + nt0 * 16 + ln15]       = c00[r];
                    sv1t[(size_t)gr0 * D + (nt0 + 1) * 16 + ln15] = c01[r];
                }
                if (gr1 < NNODES) {
                    sv1t[(size_t)gr1 * D + nt0 * 16 + ln15]       = c10[r];
                    sv1t[(size_t)gr1 * D + (nt0 + 1) * 16 + ln15] = c11[r];
                }
            }
        }
    }
}

// ---------------------------------------------------------------------------
// Main kernel: 256 threads = 4 waves, each owns 2 N-tiles (64 weight VGPRs).
// 2 nodes/iter, 8 nodes/block, launch_bounds(256,4) -> 16 waves/CU.
// Layer-1 self half folded in as per-node bias row sv1[n] (rank-1 hoist).
// ---------------------------------------------------------------------------
__global__ __launch_bounds__(256, 4) void graphrec_agg_kernel(
    const int*   __restrict__ nodes,
    const int*   __restrict__ neigh_idx,
    const int*   __restrict__ neigh_len,
    const float* __restrict__ u2e,
    const bf16*  __restrict__ u2e_bf,
    const float* __restrict__ sv1t,
    const float* __restrict__ b1,
    const float* __restrict__ b2,
    const float* __restrict__ W3,
    const float* __restrict__ b3,
    const bf16*  __restrict__ w1p,
    const bf16*  __restrict__ w2p,
    float*       __restrict__ out)
{
    __shared__ alignas(16) bf16  eu[2 * EU_NODE_E];     // 16640 B
    __shared__ alignas(16) float self_f[2 * D];         // 1024 B (A||B)
    __shared__ alignas(16) bf16  h1[2 * KN * H_STRIDE]; // 17408 B
    __shared__ float lpart[2][4 * KN];                  // 1024 B

    const int t    = threadIdx.x;
    const int lane = t & 63;
    const int wave = t >> 6;
    const int ln15 = lane & 15;
    const int quad = lane >> 4;
    const int nt0  = wave * 2;

    const float bias1_0 = b1[nt0 * 16 + ln15];
    const float bias1_1 = b1[(nt0 + 1) * 16 + ln15];
    const float bias2_0 = b2[nt0 * 16 + ln15];
    const float bias2_1 = b2[(nt0 + 1) * 16 + ln15];
    const float w3_0    = W3[nt0 * 16 + ln15];
    const float w3_1    = W3[(nt0 + 1) * 16 + ln15];
    const float b3v     = b3[0];

    // resident weight fragments: 64 VGPRs (W1 e_u half + W2)
    bf16x8 w1r[2][4];
    #pragma unroll
    for (int nt = 0; nt < 2; ++nt)
        #pragma unroll
        for (int ft = 0; ft < 4; ++ft)
            w1r[nt][ft] = *(const bf16x8*)(w1p + ((nt0 + nt) * 8 + ft) * 512 + lane * 8);
    bf16x8 w2r[2][4];
    #pragma unroll
    for (int nt = 0; nt < 2; ++nt)
        #pragma unroll
        for (int kt = 0; kt < 4; ++kt)
            w2r[nt][kt] = *(const bf16x8*)(w2p + ((nt0 + nt) * 4 + kt) * 512 + lane * 8);

    #pragma unroll 1
    for (int it = 0; it < ITERS; ++it) {
        const int nA   = blockIdx.x * 8 + it * 2;
        const int lenA = neigh_len[nA];
        const int lenB = neigh_len[nA + 1];

        // per-node self-contribution bias rows (L2/L3-hot)
        const float svA0 = sv1t[(size_t)nA * D + nt0 * 16 + ln15];
        const float svA1 = sv1t[(size_t)nA * D + (nt0 + 1) * 16 + ln15];
        const float svB0 = sv1t[(size_t)(nA + 1) * D + nt0 * 16 + ln15];
        const float svB1 = sv1t[(size_t)(nA + 1) * D + (nt0 + 1) * 16 + ln15];

        // ---- async gather: bf16 e_u direct to LDS (4 chunks/wave) ----
        {
            const int gnd = wave >> 1;
            const int cb  = (wave & 1) * 4;
            #pragma unroll
            for (int j = 0; j < 4; ++j) {
                int chunk = cb + j;
                int idx = neigh_idx[(nA + gnd) * KN + chunk + ((lane >> 4) << 3)];
                GL2LDS(u2e_bf + (size_t)idx * D + ((lane & 15) << 3),
                       eu + gnd * EU_NODE_E + chunk * CHUNK_E);
            }
            if (wave == 0) {                      // selfA||selfB fp32, ONE instr
                int sidx = nodes[nA + (lane >> 5)];
                GL2LDS(u2e + (size_t)sidx * D + ((lane & 31) << 2), self_f);
            }
        }
        __syncthreads();   // barrier 1: gather resident

        // ---- layer 1, both nodes: [32 x 128] @ [128 x 128] + sv1 bias ----
        #pragma unroll 1
        for (int nd = 0; nd < 2; ++nd) {
            const bf16* euN = eu + nd * EU_NODE_E;
            bf16* h1N = h1 + nd * KN * H_STRIDE;

            f32x4 c00 = {0.f,0.f,0.f,0.f}, c01 = c00, c10 = c00, c11 = c00;
            const int rb = (ln15 & 7) * CHUNK_E + (ln15 >> 3) * 128;
            #pragma unroll
            for (int ft = 0; ft < 4; ++ft) {
                bf16x8 a0 = *(const bf16x8*)(euN + rb + ft * 32 + quad * 8);
                bf16x8 a1 = *(const bf16x8*)(euN + rb + 256 + ft * 32 + quad * 8);
                c00 = MFMA(a0, w1r[0][ft], c00);
                c01 = MFMA(a0, w1r[1][ft], c01);
                c10 = MFMA(a1, w1r[0][ft], c10);
                c11 = MFMA(a1, w1r[1][ft], c11);
            }
            const float s0 = nd ? svB0 : svA0;
            const float s1 = nd ? svB1 : svA1;
            #pragma unroll
            for (int r = 0; r < 4; ++r) {      // relu(c + b1 + sv1) -> bf16 LDS
                int row = quad * 4 + r;
                h1N[row * H_STRIDE + nt0 * 16 + ln15]              = (bf16)fmaxf(c00[r] + bias1_0 + s0, 0.f);
                h1N[row * H_STRIDE + (nt0 + 1) * 16 + ln15]        = (bf16)fmaxf(c01[r] + bias1_1 + s1, 0.f);
                h1N[(16 + row) * H_STRIDE + nt0 * 16 + ln15]       = (bf16)fmaxf(c10[r] + bias1_0 + s0, 0.f);
                h1N[(16 + row) * H_STRIDE + (nt0 + 1) * 16 + ln15] = (bf16)fmaxf(c11[r] + bias1_1 + s1, 0.f);
            }
        }
        __syncthreads();   // barrier 2

        // ---- layer 2 + fused logits, both nodes ----
        #pragma unroll 1
        for (int nd = 0; nd < 2; ++nd) {
            const bf16* h1N = h1 + nd * KN * H_STRIDE;
            f32x4 d00 = {0.f,0.f,0.f,0.f}, d01 = d00, d10 = d00, d11 = d00;
            #pragma unroll
            for (int kt = 0; kt < 4; ++kt) {
                bf16x8 a0 = *(const bf16x8*)(h1N + ln15 * H_STRIDE + kt * 32 + quad * 8);
                bf16x8 a1 = *(const bf16x8*)(h1N + (16 + ln15) * H_STRIDE + kt * 32 + quad * 8);
                d00 = MFMA(a0, w2r[0][kt], d00);
                d01 = MFMA(a0, w2r[1][kt], d01);
                d10 = MFMA(a1, w2r[0][kt], d10);
                d11 = MFMA(a1, w2r[1][kt], d11);
            }
            #pragma unroll
            for (int r = 0; r < 4; ++r) {   // h2 never materialized
                float p0 = w3_0 * fmaxf(d00[r] + bias2_0, 0.f)
                         + w3_1 * fmaxf(d01[r] + bias2_1, 0.f);
                float p1 = w3_0 * fmaxf(d10[r] + bias2_0, 0.f)
                         + w3_1 * fmaxf(d11[r] + bias2_1, 0.f);
                #pragma unroll
                for (int o = 1; o < 16; o <<= 1) {
                    p0 += __shfl_xor(p0, o);
                    p1 += __shfl_xor(p1, o);
                }
                if (ln15 == 0) {
                    lpart[nd][wave * KN + quad * 4 + r]      = p0;
                    lpart[nd][wave * KN + 16 + quad * 4 + r] = p1;
                }
            }
        }
        __syncthreads();   // barrier 3

        // ---- per-wave softmax + vectorized aggregation ----
        // wave w: node w>>1, d-half (w&1)*64. Within wave: 8-lane group
        // g=lane>>3 owns k in {g, g+8, g+16, g+24}; lane&7 owns an 8-d segment.
        {
            const int nd    = wave >> 1;
            const int dbase = (wave & 1) * 64;
            const int g     = lane >> 3;
            const int l3    = lane & 7;
            const int k     = lane & 31;

            float lg = lpart[nd][k] + lpart[nd][KN + k] + lpart[nd][2 * KN + k]
                     + lpart[nd][3 * KN + k] + b3v;
            const int len = nd ? lenB : lenA;
            bool act = k < len;
            float l = act ? lg : -1e30f;
            float m = l;
            #pragma unroll
            for (int o = 1; o < 32; o <<= 1) m = fmaxf(m, __shfl_xor(m, o));
            float e = act ? expf(l - m) : 0.f;
            float s = e;
            #pragma unroll
            for (int o = 1; o < 32; o <<= 1) s += __shfl_xor(s, o);
            float att = (s > 0.f) ? (e / s) : 0.f;

            const bf16* euN = eu + nd * EU_NODE_E;
            float acc[8] = {0.f,0.f,0.f,0.f,0.f,0.f,0.f,0.f};
            #pragma unroll
            for (int p = 0; p < 4; ++p) {
                int kk = p * 8 + g;                      // row kk: chunk g, sub p
                float attk = __shfl(att, kk);
                bf16x8 v = *(const bf16x8*)(euN + g * CHUNK_E + p * 128 + dbase + l3 * 8);
                #pragma unroll
                for (int j = 0; j < 8; ++j) acc[j] += attk * (float)v[j];
            }
            #pragma unroll
            for (int j = 0; j < 8; ++j) {               // reduce across the 8 groups
                acc[j] += __shfl_xor(acc[j], 8);
                acc[j] += __shfl_xor(acc[j], 16);
                acc[j] += __shfl_xor(acc[j], 32);
            }
            if (g == 0) {                                // 8 lanes store 64 d coalesced
                const float* sfp = self_f + nd * D + dbase + l3 * 8;
                f32x4 sf0 = *(const f32x4*)(sfp);
                f32x4 sf1 = *(const f32x4*)(sfp + 4);
                f32x4 o0, o1;
                #pragma unroll
                for (int j = 0; j < 4; ++j) {
                    o0[j] = (len > 0) ? 0.5f * (acc[j] + sf0[j])     : sf0[j];
                    o1[j] = (len > 0) ? 0.5f * (acc[4 + j] + sf1[j]) : sf1[j];
                }
                float* op = out + (size_t)(nA + nd) * D + dbase + l3 * 8;
                *(f32x4*)(op)     = o0;
                *(f32x4*)(op + 4) = o1;
            }
        }
        __syncthreads();   // barrier 4: protect LDS for next iteration
    }
}

// ---------------------------------------------------------------------------
// Fallback (round-4 kernel, fp32 gather, no sv1) for small ws_size.
// ---------------------------------------------------------------------------
#define FB_EU_NODE_DW (16 * CHUNK_DW)

__global__ __launch_bounds__(256) void pack_weights_kernel(
    const float* __restrict__ W1, const float* __restrict__ W2,
    bf16* __restrict__ w1p, bf16* __restrict__ w2p)
{
    int t = blockIdx.x * 256 + threadIdx.x;
    if (t < 32768) {
        int j = t & 7, lane = (t >> 3) & 63, kt = (t >> 9) & 7, nt = t >> 12;
        int d = nt * 16 + (lane & 15);
        int f = kt * 32 + ((lane >> 4) << 3) + j;
        w1p[t] = (bf16)W1[d * 256 + f];
    } else if (t < 49152) {
        int u = t - 32768;
        int j = u & 7, lane = (u >> 3) & 63, kt = (u >> 9) & 3, nt = u >> 11;
        int e  = nt * 16 + (lane & 15);
        int dd = kt * 32 + ((lane >> 4) << 3) + j;
        w2p[u] = (bf16)W2[e * 128 + dd];
    }
}

__global__ __launch_bounds__(256, 3) void graphrec_agg_fb(
    const int*   __restrict__ nodes,
    const int*   __restrict__ neigh_idx,
    const int*   __restrict__ neigh_len,
    const float* __restrict__ u2e,
    const float* __restrict__ b1,
    const float* __restrict__ b2,
    const float* __restrict__ W3,
    const float* __restrict__ b3,
    const bf16*  __restrict__ w1p,
    const bf16*  __restrict__ w2p,
    float*       __restrict__ out)
{
    __shared__ alignas(16) float eu[2 * FB_EU_NODE_DW];
    __shared__ alignas(16) bf16  h1[2 * KN * H_STRIDE];
    __shared__ alignas(16) float self_f[2 * D];
    __shared__ float lpart[2][4 * KN];
    __shared__ float att_s[2][KN];

    const int t    = threadIdx.x;
    const int lane = t & 63;
    const int wave = t >> 6;
    const int ln15 = lane & 15;
    const int quad = lane >> 4;
    const int nt0  = wave * 2;

    const float bias1_0 = b1[nt0 * 16 + ln15];
    const float bias1_1 = b1[(nt0 + 1) * 16 + ln15];
    const float bias2_0 = b2[nt0 * 16 + ln15];
    const float bias2_1 = b2[(nt0 + 1) * 16 + ln15];
    const float w3_0    = W3[nt0 * 16 + ln15];
    const float w3_1    = W3[(nt0 + 1) * 16 + ln15];
    const float b3v     = b3[0];

    bf16x8 w1r[2][8];
    #pragma unroll
    for (int nt = 0; nt < 2; ++nt)
        #pragma unroll
        for (int ft = 0; ft < 8; ++ft)
            w1r[nt][ft] = *(const bf16x8*)(w1p + ((nt0 + nt) * 8 + ft) * 512 + lane * 8);
    bf16x8 w2r[2][4];
    #pragma unroll
    for (int nt = 0; nt < 2; ++nt)
        #pragma unroll
        for (int kt = 0; kt < 4; ++kt)
            w2r[nt][kt] = *(const bf16x8*)(w2p + ((nt0 + nt) * 4 + kt) * 512 + lane * 8);

    #pragma unroll 1
    for (int it = 0; it < ITERS; ++it) {
        const int nA   = blockIdx.x * 8 + it * 2;
        const int lenA = neigh_len[nA];
        const int lenB = neigh_len[nA + 1];
        {
            const int half = lane >> 5;
            const int colb = (lane & 31) << 4;
            #pragma unroll
            for (int nd = 0; nd < 2; ++nd) {
                #pragma unroll
                for (int j = 0; j < 4; ++j) {
                    int chunk = wave * 4 + j;
                    int idx = neigh_idx[(nA + nd) * KN + chunk + (half << 4)];
                    const char* src = (const char*)(u2e + (size_t)idx * D) + colb;
                    GL2LDS(src, eu + nd * FB_EU_NODE_DW + chunk * CHUNK_DW);
                }
            }
            if (wave == 0) {
                int sidx = nodes[nA + half];
                const char* src = (const char*)(u2e + (size_t)sidx * D) + colb;
                GL2LDS(src, self_f);
            }
        }
        __syncthreads();
        #pragma unroll 1
        for (int nd = 0; nd < 2; ++nd) {
            const float* euN = eu + nd * FB_EU_NODE_DW;
            const float* sfN = self_f + nd * D;
            bf16* h1N = h1 + nd * KN * H_STRIDE;
            f32x4 c00 = {0.f,0.f,0.f,0.f}, c01 = c00, c10 = c00, c11 = c00;
            const int r0 = ln15 * CHUNK_DW;
            #pragma unroll
            for (int ft = 0; ft < 4; ++ft) {
                int off = ft * 32 + quad * 8;
                f32x4 u0 = *(const f32x4*)(euN + r0 + off);
                f32x4 u1 = *(const f32x4*)(euN + r0 + off + 4);
                f32x4 v0 = *(const f32x4*)(euN + r0 + 128 + off);
                f32x4 v1 = *(const f32x4*)(euN + r0 + 128 + off + 4);
                bf16x8 a0, a1;
                #pragma unroll
                for (int e = 0; e < 4; ++e) {
                    a0[e] = (bf16)u0[e]; a0[4 + e] = (bf16)u1[e];
                    a1[e] = (bf16)v0[e]; a1[4 + e] = (bf16)v1[e];
                }
                c00 = MFMA(a0, w1r[0][ft], c00);
                c01 = MFMA(a0, w1r[1][ft], c01);
                c10 = MFMA(a1, w1r[0][ft], c10);
                c11 = MFMA(a1, w1r[1][ft], c11);
            }
            #pragma unroll
            for (int ft = 4; ft < 8; ++ft) {
                int off = (ft - 4) * 32 + quad * 8;
                f32x4 u0 = *(const f32x4*)(sfN + off);
                f32x4 u1 = *(const f32x4*)(sfN + off + 4);
                bf16x8 a;
                #pragma unroll
                for (int e = 0; e < 4; ++e) { a[e] = (bf16)u0[e]; a[4 + e] = (bf16)u1[e]; }
                c00 = MFMA(a, w1r[0][ft], c00);
                c01 = MFMA(a, w1r[1][ft], c01);
                c10 = MFMA(a, w1r[0][ft], c10);
                c11 = MFMA(a, w1r[1][ft], c11);
            }
            #pragma unroll
            for (int r = 0; r < 4; ++r) {
                int row = quad * 4 + r;
                h1N[row * H_STRIDE + nt0 * 16 + ln15]              = (bf16)fmaxf(c00[r] + bias1_0, 0.f);
                h1N[row * H_STRIDE + (nt0 + 1) * 16 + ln15]        = (bf16)fmaxf(c01[r] + bias1_1, 0.f);
                h1N[(16 + row) * H_STRIDE + nt0 * 16 + ln15]       = (bf16)fmaxf(c10[r] + bias1_0, 0.f);
                h1N[(16 + row) * H_STRIDE + (nt0 + 1) * 16 + ln15] = (bf16)fmaxf(c11[r] + bias1_1, 0.f);
            }
        }
        __syncthreads();
        #pragma unroll 1
        for (int nd = 0; nd < 2; ++nd) {
            const bf16* h1N = h1 + nd * KN * H_STRIDE;
            f32x4 d00 = {0.f,0.f,0.f,0.f}, d01 = d00, d10 = d00, d11 = d00;
            #pragma unroll
            for (int kt = 0; kt < 4; ++kt) {
                bf16x8 a0 = *(const bf16x8*)(h1N + ln15 * H_STRIDE + kt * 32 + quad * 8);
                bf16x8 a1 = *(const bf16x8*)(h1N + (16 + ln15) * H_STRIDE + kt * 32 + quad * 8);
                d00 = MFMA(a0, w2r[0][kt], d00);
                d01 = MFMA(a0, w2r[1][kt], d01);
                d10 = MFMA(a1, w2r[0][kt], d10);
                d11 = MFMA(a1, w2r[1][kt], d11);
            }
            #pragma unroll
            for (int r = 0; r < 4; ++r) {
                float p0 = w3_0 * fmaxf(d00[r] + bias2_0, 0.f)
                         + w3_1 * fmaxf(d01[r] + bias2_1, 0.f);
                float p1 = w3_0 * fmaxf(d10[r] + bias2_0, 0.f)
                         + w3_1 * fmaxf(d11[r] + bias2_1, 0.f);
                #pragma unroll
                for (int o = 1; o < 16; o <<= 1) {
                    p0 += __shfl_xor(p0, o);
                    p1 += __shfl_xor(p1, o);
                }
                if (ln15 == 0) {
                    lpart[nd][wave * KN + quad * 4 + r]      = p0;
                    lpart[nd][wave * KN + 16 + quad * 4 + r] = p1;
                }
            }
        }
        __syncthreads();
        if (wave < 2) {
            int nd = wave, k = lane & 31;
            float lg = lpart[nd][k] + lpart[nd][KN + k] + lpart[nd][2 * KN + k]
                     + lpart[nd][3 * KN + k] + b3v;
            int len = nd ? lenB : lenA;
            bool act = (lane < 32) && (k < len);
            float l = act ? lg : -1e30f;
            float m = l;
            #pragma unroll
            for (int o = 1; o < 32; o <<= 1) m = fmaxf(m, __shfl_xor(m, o));
            float e = act ? expf(l - m) : 0.f;
            float s = e;
            #pragma unroll
            for (int o = 1; o < 32; o <<= 1) s += __shfl_xor(s, o);
            if (lane < 32) att_s[nd][k] = (s > 0.f) ? (e / s) : 0.f;
        }
        __syncthreads();
        {
            int nd = t >> 7, d = t & 127;
            const float* euN = eu + nd * FB_EU_NODE_DW;
            float acc = 0.f;
            #pragma unroll
            for (int k = 0; k < KN; ++k)
                acc += att_s[nd][k] * euN[(k & 15) * CHUNK_DW + ((k >> 4) << 7) + d];
            float sf = self_f[nd * D + d];
            int len = nd ? lenB : lenA;
            out[(size_t)(nA + nd) * D + d] = (len > 0) ? 0.5f * (acc + sf) : sf;
        }
        __syncthreads();
    }
}

extern "C" void kernel_launch(void* const* d_in, const int* in_sizes, int n_in,
                              void* d_out, int out_size, void* d_ws, size_t ws_size,
                              hipStream_t stream) {
    const int*   nodes     = (const int*)d_in[0];
    const int*   neigh_idx = (const int*)d_in[1];
    const int*   neigh_len = (const int*)d_in[2];
    const float* u2e       = (const float*)d_in[3];
    const float* W1        = (const float*)d_in[4];
    const float* b1        = (const float*)d_in[5];
    const float* W2        = (const float*)d_in[6];
    const float* b2        = (const float*)d_in[7];
    const float* W3        = (const float*)d_in[8];
    const float* b3        = (const float*)d_in[9];
    float* out = (float*)d_out;

    bf16*  w1p    = (bf16*)d_ws;                                  // 65536 B
    bf16*  w2p    = w1p + 32768;                                  // 32768 B
    bf16*  u2e_bf = (bf16*)((char*)d_ws + 98304);                 // 25.6 MB
    float* sv1t   = (float*)((char*)d_ws + 98304 + (size_t)VOCAB * D * 2); // 10.24 MB
    const size_t need = 98304ull + (size_t)VOCAB * D * 2 + (size_t)NNODES * D * 4;

    if (ws_size >= need) {
        aux_kernel<<<AUX_BLOCKS, 256, 0, stream>>>(u2e, W1, W2, nodes,
                                                   u2e_bf, w1p, w2p, sv1t);
        graphrec_agg_kernel<<<GRID, 256, 0, stream>>>(nodes, neigh_idx, neigh_len,
                                                      u2e, u2e_bf, sv1t, b1, b2,
                                                      W3, b3, w1p, w2p, out);
    } else {
        pack_weights_kernel<<<192, 256, 0, stream>>>(W1, W2, w1p, w2p);
        graphrec_agg_fb<<<GRID, 256, 0, stream>>>(nodes, neigh_idx, neigh_len, u2e,
                                                  b1, b2, W3, b3, w1p, w2p, out);
    }
}